// Round 7
// baseline (4880.216 us; speedup 1.0000x reference)
//
#include <hip/hip_runtime.h>
#include <hip/hip_bf16.h>

typedef _Float16 half2v __attribute__((ext_vector_type(2)));
typedef _Float16 half8v __attribute__((ext_vector_type(8)));
typedef float float4v __attribute__((ext_vector_type(4)));
typedef unsigned int u32;
typedef unsigned short u16;

#define DEV static __device__ __forceinline__

DEV u32 pack2(float a, float b) {
  half2v h = { (_Float16)a, (_Float16)b };
  return __builtin_bit_cast(u32, h);
}
DEV half2v uph(u32 u) { return __builtin_bit_cast(half2v, u); }
DEV u16 ftoh16(float f) { return __builtin_bit_cast(u16, (_Float16)f); }
DEV float h16tof(u16 s) { return (float)__builtin_bit_cast(_Float16, s); }

#if __has_builtin(__builtin_amdgcn_fdot2)
DEV float fdot2(half2v a, half2v b, float c) { return __builtin_amdgcn_fdot2(a, b, c, false); }
#else
DEV float fdot2(half2v a, half2v b, float c) {
  return c + (float)a.x * (float)b.x + (float)a.y * (float)b.y;
}
#endif

DEV float fast_rcp(float x) { return __builtin_amdgcn_rcpf(x); }
DEV float sigmoid_f(float x) { return fast_rcp(1.f + exp2f(-1.4426950408889634f * x)); }
DEV float tanh_f(float x) {
  float e = exp2f(x * 2.8853900817779268f);  // e^(2x)
  return 1.f - 2.f * fast_rcp(e + 1.f);
}

// Raw barrier: LDS-publish only. Deliberately NO vmcnt(0) — in-flight global
// loads/stores keep flying across it (the compiler's own data-dep vmcnt(N)
// drains them right before their LDS write, ~2-3 steps after issue).
DEV void barrier_lgkm() {
  __asm__ __volatile__("s_waitcnt lgkmcnt(0)\ns_barrier" ::: "memory");
}

// ---------------------------------------------------------------------------
// Prep: transpose + f16-convert the three weight matrices (dst[c][r] = src[r][c])
// ---------------------------------------------------------------------------
__global__ void prep_transpose(const float* __restrict__ Wz, const float* __restrict__ Wh,
                               const float* __restrict__ Wo, _Float16* __restrict__ Wzt,
                               _Float16* __restrict__ Wht, _Float16* __restrict__ Wot)
{
  const float* src; _Float16* dst; int R, C;
  if (blockIdx.y == 0)      { src = Wz; dst = Wzt; R = 128; C = 256; }
  else if (blockIdx.y == 1) { src = Wh; dst = Wht; R = 128; C = 256; }
  else                      { src = Wo; dst = Wot; R = 256; C = 128; }
  int total = R * C;
  for (int idx = blockIdx.x * blockDim.x + threadIdx.x; idx < total;
       idx += gridDim.x * blockDim.x) {
    int rr = idx / C, cc = idx % C;
    dst[(size_t)cc * R + rr] = (_Float16)src[idx];
  }
}

// ---------------------------------------------------------------------------
// MFMA GEMM: out[M x N] = A[M x K] * Bt^T (+bias). Bt is [N][K] f16 (pre-transposed).
// ---------------------------------------------------------------------------
template <int K, int N, bool A_F32, bool OUT_F16>
__global__ __launch_bounds__(256, 2) void gemm_mfma(
    const void* __restrict__ A_, const _Float16* __restrict__ Bt,
    const float* __restrict__ bias, void* __restrict__ out)
{
  __shared__ _Float16 Blds[N * K];  // 64 KB

  const int tid = threadIdx.x;
  constexpr int CHUNKS = K / 8;
  constexpr int ITER = (N * K / 8) / 256;
#pragma unroll
  for (int i = 0; i < ITER; ++i) {
    int idx = tid + i * 256;
    int n = idx / CHUNKS;
    int c = idx % CHUNKS;
    int cs = c ^ (n & 7);
    *(uint4*)(Blds + (size_t)n * K + cs * 8) =
        *(const uint4*)(Bt + (size_t)n * K + c * 8);
  }
  __syncthreads();

  const int w = tid >> 6, l = tid & 63;
  const int lm = l & 15, lq = l >> 4;
  const size_t m0 = (size_t)blockIdx.x * 128;

  float4v acc[2][N / 16] = {};

#pragma unroll
  for (int kk = 0; kk < K / 32; ++kk) {
    const int kbase = kk * 32 + lq * 8;
    half8v af[2];
#pragma unroll
    for (int ms = 0; ms < 2; ++ms) {
      const size_t row = m0 + (size_t)(w * 2 + ms) * 16 + lm;
      if constexpr (A_F32) {
        const float* ap = (const float*)A_ + row * K + kbase;
        float4 x0 = *(const float4*)ap;
        float4 x1 = *(const float4*)(ap + 4);
        af[ms] = half8v{(_Float16)x0.x, (_Float16)x0.y, (_Float16)x0.z, (_Float16)x0.w,
                        (_Float16)x1.x, (_Float16)x1.y, (_Float16)x1.z, (_Float16)x1.w};
      } else {
        af[ms] = *(const half8v*)((const _Float16*)A_ + row * K + kbase);
      }
    }
    const int c = kk * 4 + lq;
#pragma unroll
    for (int nt = 0; nt < N / 16; ++nt) {
      const int n = nt * 16 + lm;
      half8v bf = *(const half8v*)(Blds + (size_t)n * K + (c ^ (lm & 7)) * 8);
      acc[0][nt] = __builtin_amdgcn_mfma_f32_16x16x32_f16(af[0], bf, acc[0][nt], 0, 0, 0);
      acc[1][nt] = __builtin_amdgcn_mfma_f32_16x16x32_f16(af[1], bf, acc[1][nt], 0, 0, 0);
    }
  }

#pragma unroll
  for (int ms = 0; ms < 2; ++ms) {
    const size_t rowbase = m0 + (size_t)(w * 2 + ms) * 16 + lq * 4;
#pragma unroll
    for (int nt = 0; nt < N / 16; ++nt) {
      const int col = nt * 16 + lm;
      const float bcol = bias[col];
#pragma unroll
      for (int rr = 0; rr < 4; ++rr) {
        const size_t row = rowbase + rr;
        float v = acc[ms][nt][rr] + bcol;
        if constexpr (OUT_F16) ((_Float16*)out)[row * N + col] = (_Float16)v;
        else                   ((float*)out)[row * N + col] = v;
      }
    }
  }
}

// ---------------------------------------------------------------------------
// Sequential scan. One WG (512 thr, 8 waves) per TWO batch elements.
//  The scan is latency-bound (r2/r3/r5 all ~1400 cy/step with pipes <50%
//  busy), so each block now runs TWO independent batch chains interleaved in
//  the same waves: batch B's reads/fdot2/shuffles fill batch A's dependency
//  stalls between the shared barriers. Register-resident weights (Uh slices /
//  Uz fragments, 128 VGPR) are batch-invariant and SHARED; only LDS state and
//  a few scalars duplicate (LDS 2x ~21 KB = 41.7 KB).
//  Per-batch structure is byte-identical to the verified r5 kernel:
//  g0 (waves 0-3): candidate gate via 4-slice fdot2 (lane q-slice k=[q*64,
//    q*64+64), 8 ds_read_b128) + ownership-pruned butterfly reduce
//    (4x shfl_xor(32) + 2x shfl_xor(16)). zn = z_{t+1} prefetched at step
//    START for u<3 (slot-disjoint from the u3 z-burst writes).
//  g1 (waves 4-7): z gate via MFMA burst once per 4 steps (u==3); all global
//    traffic issued at u==0 into registers, ds_written to LDS at u==2.
//  Barriers: 5 per 4-step group (B0..B3 + B4), unchanged.
// ---------------------------------------------------------------------------
__global__ __launch_bounds__(512, 1) void scan_kernel(
    const u32* __restrict__ xz32, const u32* __restrict__ xh32,
    const float* __restrict__ Uz, const float* __restrict__ Uh,
    u32* __restrict__ hsOut)
{
  const int tid = threadIdx.x;
  const int w   = tid >> 6;
  const int l   = tid & 63;
  const int g   = w >> 2;
  const int wv  = w & 3;

  // pitch 264 u16 (=528B): ring slots are 4 banks apart.
  __shared__ __align__(16) u16 histS[2][8][264];   // h_t
  __shared__ __align__(16) u16 zringS[2][8][264];  // z_t
  __shared__ __align__(16) u16 zhS[2][8][264];     // z_t * h_{t-1}
  __shared__ __align__(16) u16 xhS[2][2][1024];    // xh staging
  __shared__ __align__(16) u16 xzS[2][2][1024];    // xz staging

  uint4 W[32];  // g0: fdot2 weights W[nt*8+i] (col wv*64+nt*16+lm, k=q*64+i*8)
                // g1: Uz B-frags W[kt*4+nt]   — SHARED across both batches

  const int b0 = blockIdx.x * 2, b1 = b0 + 1;
  const size_t xbA = (size_t)b0 * 4096 * 128;   // u32 units
  const size_t xbB = (size_t)b1 * 4096 * 128;
  const u16* xz16v = (const u16*)xz32;
  const int c   = wv * 64 + l;        // g0: owned column / g1: linear id
  const int rr  = c >> 6;             // staging row 0..3
  const int c4  = (c & 63) * 4;       // staging col (u16), 4 per thread
  const int lm  = l & 15;
  const int q   = l >> 4;
  const int koff = q * 8;             // g1 A-frag k-slice

  if (g == 0) {
    // 4-slice fdot2 weights (Uh)
#pragma unroll
    for (int nt = 0; nt < 4; ++nt) {
      const int cn = wv * 64 + nt * 16 + lm;
#pragma unroll
      for (int i = 0; i < 8; ++i) {
        u32 q2[4];
#pragma unroll
        for (int p2 = 0; p2 < 4; ++p2) {
          int k0 = q * 64 + i * 8 + 2 * p2;
          q2[p2] = pack2(Uh[(size_t)k0 * 256 + cn], Uh[(size_t)(k0 + 1) * 256 + cn]);
        }
        W[nt * 8 + i] = make_uint4(q2[0], q2[1], q2[2], q2[3]);
      }
    }
  } else {
    // Uz -> B-fragments: W[kt*4+nt], B[k=kt*32+(l>>4)*8+j][n=wv*64+nt*16+(l&15)]
#pragma unroll
    for (int kt = 0; kt < 8; ++kt)
#pragma unroll
      for (int nt = 0; nt < 4; ++nt) {
        u32 q2[4];
#pragma unroll
        for (int p2 = 0; p2 < 4; ++p2) {
          int k0 = kt * 32 + koff + 2 * p2;
          int cn = wv * 64 + nt * 16 + lm;
          q2[p2] = pack2(Uz[(size_t)k0 * 256 + cn], Uz[(size_t)(k0 + 1) * 256 + cn]);
        }
        W[kt * 4 + nt] = make_uint4(q2[0], q2[1], q2[2], q2[3]);
      }
  }

  // zero h_{-4..-1} (slots 4..7) and zh_0 for both batches
#pragma unroll
  for (int s = 0; s < 2; ++s) {
    for (int i = tid; i < 4 * 264; i += 512) (&histS[s][4][0])[i] = 0;
    for (int i = tid; i < 264; i += 512) zhS[s][0][i] = 0;
  }

  if (g == 1) {
    // z_0..3 = sigmoid(xz rows 0..3);  stage xh rows 0..3, xz rows 4..7
#pragma unroll
    for (int s = 0; s < 2; ++s) {
      const size_t xb = s ? xbB : xbA;
      const size_t bt = (size_t)(s ? b1 : b0) * 4096;
      uint2 xzv = *(const uint2*)&xz16v[(bt + rr) * 256 + c4];
      half2v a0 = uph(xzv.x), a1 = uph(xzv.y);
      u32 z01 = pack2(sigmoid_f((float)a0.x), sigmoid_f((float)a0.y));
      u32 z23 = pack2(sigmoid_f((float)a1.x), sigmoid_f((float)a1.y));
      *(uint2*)&zringS[s][rr][c4] = make_uint2(z01, z23);
      *(uint2*)&xhS[s][0][rr * 256 + c4] =
          *(const uint2*)&xh32[xb + (size_t)rr * 128 + (c & 63) * 2];
      *(uint2*)&xzS[s][0][rr * 256 + c4] =
          *(const uint2*)&xz16v[(bt + 4 + rr) * 256 + c4];
    }
  }
  float hA = 0.f, hB = 0.f;
  __syncthreads();

  for (int tb = 0; tb < 4096; tb += 4) {
    const int p = (tb >> 2) & 1;
    uint2 xhvA, xzvA, xhvB, xzvB;         // g1: staged in regs u0 -> u2
#pragma unroll
    for (int u = 0; u < 4; ++u) {
      const int t = tb + u;
      if (g == 0) {
        // ------------- candidate gate: column c, batches A & B -------------
        float xh_tA = h16tof(xhS[0][p][u * 256 + c]);
        float xh_tB = h16tof(xhS[1][p][u * 256 + c]);
        float z_tA  = h16tof(zringS[0][t & 7][c]);
        float z_tB  = h16tof(zringS[1][t & 7][c]);
        // prefetch z_{t+1} (u<3): published >=1 group ago; slots disjoint
        // from this group's burst writes.
        u16 znA = 0, znB = 0;
        if (u < 3) {
          znA = zringS[0][(t + 1) & 7][c];
          znB = zringS[1][(t + 1) & 7][c];
        }
        const uint4* a4A = (const uint4*)&zhS[0][t & 7][q * 64];
        const uint4* a4B = (const uint4*)&zhS[1][t & 7][q * 64];
        float sA0 = 0.f, sA1 = 0.f, sA2 = 0.f, sA3 = 0.f;
        float sB0 = 0.f, sB1 = 0.f, sB2 = 0.f, sB3 = 0.f;
#pragma unroll
        for (int i = 0; i < 8; ++i) {
          uint4 A = a4A[i];
          uint4 Bv = a4B[i];
          uint4 w0 = W[0 * 8 + i], w1 = W[1 * 8 + i];
          uint4 w2 = W[2 * 8 + i], w3 = W[3 * 8 + i];
          sA0 = fdot2(uph(A.x), uph(w0.x), sA0);
          sA0 = fdot2(uph(A.y), uph(w0.y), sA0);
          sA0 = fdot2(uph(A.z), uph(w0.z), sA0);
          sA0 = fdot2(uph(A.w), uph(w0.w), sA0);
          sB0 = fdot2(uph(Bv.x), uph(w0.x), sB0);
          sB0 = fdot2(uph(Bv.y), uph(w0.y), sB0);
          sB0 = fdot2(uph(Bv.z), uph(w0.z), sB0);
          sB0 = fdot2(uph(Bv.w), uph(w0.w), sB0);
          sA1 = fdot2(uph(A.x), uph(w1.x), sA1);
          sA1 = fdot2(uph(A.y), uph(w1.y), sA1);
          sA1 = fdot2(uph(A.z), uph(w1.z), sA1);
          sA1 = fdot2(uph(A.w), uph(w1.w), sA1);
          sB1 = fdot2(uph(Bv.x), uph(w1.x), sB1);
          sB1 = fdot2(uph(Bv.y), uph(w1.y), sB1);
          sB1 = fdot2(uph(Bv.z), uph(w1.z), sB1);
          sB1 = fdot2(uph(Bv.w), uph(w1.w), sB1);
          sA2 = fdot2(uph(A.x), uph(w2.x), sA2);
          sA2 = fdot2(uph(A.y), uph(w2.y), sA2);
          sA2 = fdot2(uph(A.z), uph(w2.z), sA2);
          sA2 = fdot2(uph(A.w), uph(w2.w), sA2);
          sB2 = fdot2(uph(Bv.x), uph(w2.x), sB2);
          sB2 = fdot2(uph(Bv.y), uph(w2.y), sB2);
          sB2 = fdot2(uph(Bv.z), uph(w2.z), sB2);
          sB2 = fdot2(uph(Bv.w), uph(w2.w), sB2);
          sA3 = fdot2(uph(A.x), uph(w3.x), sA3);
          sA3 = fdot2(uph(A.y), uph(w3.y), sA3);
          sA3 = fdot2(uph(A.z), uph(w3.z), sA3);
          sA3 = fdot2(uph(A.w), uph(w3.w), sA3);
          sB3 = fdot2(uph(Bv.x), uph(w3.x), sB3);
          sB3 = fdot2(uph(Bv.y), uph(w3.y), sB3);
          sB3 = fdot2(uph(Bv.z), uph(w3.z), sB3);
          sB3 = fdot2(uph(Bv.w), uph(w3.w), sB3);
        }
        // Cross-quad reduce, batch A and B independently.
        float tA0 = sA0 + __shfl_xor(sA0, 32);
        float tA1 = sA1 + __shfl_xor(sA1, 32);
        float tA2 = sA2 + __shfl_xor(sA2, 32);
        float tA3 = sA3 + __shfl_xor(sA3, 32);
        float tB0 = sB0 + __shfl_xor(sB0, 32);
        float tB1 = sB1 + __shfl_xor(sB1, 32);
        float tB2 = sB2 + __shfl_xor(sB2, 32);
        float tB3 = sB3 + __shfl_xor(sB3, 32);
        float cA0 = (q & 2) ? tA2 : tA0;
        float cA1 = (q & 2) ? tA3 : tA1;
        float cB0 = (q & 2) ? tB2 : tB0;
        float cB1 = (q & 2) ? tB3 : tB1;
        cA0 += __shfl_xor(cA0, 16);
        cA1 += __shfl_xor(cA1, 16);
        cB0 += __shfl_xor(cB0, 16);
        cB1 += __shfl_xor(cB1, 16);
        float preA = (q & 1) ? cA1 : cA0;
        float preB = (q & 1) ? cB1 : cB0;

        float htlA = tanh_f(preA + xh_tA);
        float htlB = tanh_f(preB + xh_tB);
        hA += z_tA * (htlA - hA);
        hB += z_tB * (htlB - hB);
        histS[0][t & 7][c] = ftoh16(hA);
        histS[1][t & 7][c] = ftoh16(hB);
        if (u < 3) {
          zhS[0][(t + 1) & 7][c] = ftoh16(h16tof(znA) * hA);
          zhS[1][(t + 1) & 7][c] = ftoh16(h16tof(znB) * hB);
        }
        barrier_lgkm();                   // B_u
        if (u == 3) {                     // B3 published z_{tb+4}; finish zh
          float zn0 = h16tof(zringS[0][(t + 1) & 7][c]);
          float zn1 = h16tof(zringS[1][(t + 1) & 7][c]);
          zhS[0][(t + 1) & 7][c] = ftoh16(zn0 * hA);
          zhS[1][(t + 1) & 7][c] = ftoh16(zn1 * hB);
          barrier_lgkm();                 // B4
        }
      } else {
        // ---------------- z gate + all global traffic ----------------
        if (u == 0) {
          int rh = tb + 4 + rr; if (rh > 4095) rh = 4095;
          int rz = tb + 8 + rr; if (rz > 4095) rz = 4095;
          xhvA = *(const uint2*)&xh32[xbA + (size_t)rh * 128 + (c & 63) * 2];
          xhvB = *(const uint2*)&xh32[xbB + (size_t)rh * 128 + (c & 63) * 2];
          xzvA = *(const uint2*)&xz16v[((size_t)b0 * 4096 + rz) * 256 + c4];
          xzvB = *(const uint2*)&xz16v[((size_t)b1 * 4096 + rz) * 256 + c4];
          if (tb > 0) {                   // write back h rows tb-4..tb-1
            int ro = tb - 4 + rr;
            uint2 hvA = *(const uint2*)&histS[0][ro & 7][c4];
            uint2 hvB = *(const uint2*)&histS[1][ro & 7][c4];
            *(uint2*)&hsOut[xbA + (size_t)ro * 128 + (c & 63) * 2] = hvA;
            *(uint2*)&hsOut[xbB + (size_t)ro * 128 + (c & 63) * 2] = hvB;
          }
          barrier_lgkm();
        } else if (u == 2) {
          // publish staged xh/xz (vmcnt wait lands here, ~2 steps late)
          *(uint2*)&xhS[0][p ^ 1][rr * 256 + c4] = xhvA;
          *(uint2*)&xhS[1][p ^ 1][rr * 256 + c4] = xhvB;
          *(uint2*)&xzS[0][p ^ 1][rr * 256 + c4] = xzvA;
          *(uint2*)&xzS[1][p ^ 1][rr * 256 + c4] = xzvB;
          barrier_lgkm();                 // B2
        } else if (u == 3) {
          // MFMA burst: z_{tb+4+r2} = sigmoid(xz + h_{tb-1+r2} @ Uz), both b.
          const int srow = (tb + 7 + (l & 3)) & 7;   // m%4 row select
#pragma unroll
          for (int s = 0; s < 2; ++s) {
            float4v acc4[4] = {};
#pragma unroll
            for (int kt = 0; kt < 8; ++kt) {
              half8v a = __builtin_bit_cast(
                  half8v, *(const uint4*)&histS[s][srow][kt * 32 + koff]);
#pragma unroll
              for (int nt = 0; nt < 4; ++nt)
                acc4[nt] = __builtin_amdgcn_mfma_f32_16x16x32_f16(
                    a, __builtin_bit_cast(half8v, W[kt * 4 + nt]), acc4[nt], 0, 0, 0);
            }
            // quad q handles time-row q wave-uniformly (4 sigmoids/lane).
#pragma unroll
            for (int nt = 0; nt < 4; ++nt) {
              float4v a = acc4[nt];
              float pre = q == 0 ? a[0] : q == 1 ? a[1] : q == 2 ? a[2] : a[3];
              int cn = wv * 64 + nt * 16 + lm;
              float zv = sigmoid_f(pre + h16tof(xzS[s][p][q * 256 + cn]));
              zringS[s][(tb + 4 + q) & 7][cn] = ftoh16(zv);
            }
          }
          barrier_lgkm();                 // B3
          barrier_lgkm();                 // B4
        } else {
          barrier_lgkm();                 // B1
        }
      }
    }
  }

  // tail: write back h rows 4092..4095
  if (g == 1) {
    int ro = 4092 + rr;
    uint2 hvA = *(const uint2*)&histS[0][ro & 7][c4];
    uint2 hvB = *(const uint2*)&histS[1][ro & 7][c4];
    *(uint2*)&hsOut[xbA + (size_t)ro * 128 + (c & 63) * 2] = hvA;
    *(uint2*)&hsOut[xbB + (size_t)ro * 128 + (c & 63) * 2] = hvB;
  }
}

// ---------------------------------------------------------------------------
extern "C" void kernel_launch(void* const* d_in, const int* in_sizes, int n_in,
                              void* d_out, int out_size, void* d_ws, size_t ws_size,
                              hipStream_t stream)
{
  (void)in_sizes; (void)n_in; (void)out_size; (void)ws_size;
  const float* x  = (const float*)d_in[0];
  const float* Wz = (const float*)d_in[1];
  const float* Uz = (const float*)d_in[2];
  const float* bz = (const float*)d_in[3];
  const float* Wh = (const float*)d_in[4];
  const float* Uh = (const float*)d_in[5];
  const float* bh = (const float*)d_in[6];
  const float* Wo = (const float*)d_in[7];
  const float* bo = (const float*)d_in[8];

  char* ws = (char*)d_ws;
  _Float16* Wzt  = (_Float16*)(ws);                                   // 64 KB
  _Float16* Wht  = (_Float16*)(ws + (64 << 10));                      // 64 KB
  _Float16* Wot  = (_Float16*)(ws + (128 << 10));                     // 64 KB
  _Float16* xz16 = (_Float16*)(ws + (256 << 10));                     // 64 MB
  _Float16* xh16 = (_Float16*)(ws + (256 << 10) + (size_t)64 * 1024 * 1024); // 64 MB

  _Float16* hs16 = (_Float16*)d_out;  // hs staged in d_out; head GEMM in-place

  prep_transpose<<<dim3(32, 3), 256, 0, stream>>>(Wz, Wh, Wo, Wzt, Wht, Wot);
  gemm_mfma<128, 256, true, true><<<1024, 256, 0, stream>>>(x, Wzt, bz, xz16);
  gemm_mfma<128, 256, true, true><<<1024, 256, 0, stream>>>(x, Wht, bh, xh16);
  scan_kernel<<<16, 512, 0, stream>>>((const u32*)xz16, (const u32*)xh16,
                                      Uz, Uh, (u32*)d_out);
  gemm_mfma<256, 128, false, false><<<1024, 256, 0, stream>>>(hs16, Wot, bo, d_out);
}

// Round 8
// 2944.099 us; speedup vs baseline: 1.6576x; 1.6576x over previous
//
#include <hip/hip_runtime.h>
#include <hip/hip_bf16.h>

typedef _Float16 half2v __attribute__((ext_vector_type(2)));
typedef _Float16 half8v __attribute__((ext_vector_type(8)));
typedef float float4v __attribute__((ext_vector_type(4)));
typedef unsigned int u32;
typedef unsigned short u16;

#define DEV static __device__ __forceinline__

DEV u32 pack2(float a, float b) {
  half2v h = { (_Float16)a, (_Float16)b };
  return __builtin_bit_cast(u32, h);
}
DEV half2v uph(u32 u) { return __builtin_bit_cast(half2v, u); }
DEV u16 ftoh16(float f) { return __builtin_bit_cast(u16, (_Float16)f); }
DEV float h16tof(u16 s) { return (float)__builtin_bit_cast(_Float16, s); }

#if __has_builtin(__builtin_amdgcn_fdot2)
DEV float fdot2(half2v a, half2v b, float c) { return __builtin_amdgcn_fdot2(a, b, c, false); }
#else
DEV float fdot2(half2v a, half2v b, float c) {
  return c + (float)a.x * (float)b.x + (float)a.y * (float)b.y;
}
#endif

DEV float fast_rcp(float x) { return __builtin_amdgcn_rcpf(x); }
DEV float sigmoid_f(float x) { return fast_rcp(1.f + exp2f(-1.4426950408889634f * x)); }
DEV float tanh_f(float x) {
  float e = exp2f(x * 2.8853900817779268f);  // e^(2x)
  return 1.f - 2.f * fast_rcp(e + 1.f);
}

// Raw barrier: LDS-publish only. Deliberately NO vmcnt(0) — in-flight global
// loads/stores keep flying across it (the compiler's own data-dep vmcnt(N)
// drains them right before their LDS write, ~2 steps after issue).
DEV void barrier_lgkm() {
  __asm__ __volatile__("s_waitcnt lgkmcnt(0)\ns_barrier" ::: "memory");
}

// ---------------------------------------------------------------------------
// Prep: transpose + f16-convert the three weight matrices (dst[c][r] = src[r][c])
// ---------------------------------------------------------------------------
__global__ void prep_transpose(const float* __restrict__ Wz, const float* __restrict__ Wh,
                               const float* __restrict__ Wo, _Float16* __restrict__ Wzt,
                               _Float16* __restrict__ Wht, _Float16* __restrict__ Wot)
{
  const float* src; _Float16* dst; int R, C;
  if (blockIdx.y == 0)      { src = Wz; dst = Wzt; R = 128; C = 256; }
  else if (blockIdx.y == 1) { src = Wh; dst = Wht; R = 128; C = 256; }
  else                      { src = Wo; dst = Wot; R = 256; C = 128; }
  int total = R * C;
  for (int idx = blockIdx.x * blockDim.x + threadIdx.x; idx < total;
       idx += gridDim.x * blockDim.x) {
    int rr = idx / C, cc = idx % C;
    dst[(size_t)cc * R + rr] = (_Float16)src[idx];
  }
}

// ---------------------------------------------------------------------------
// MFMA GEMM: out[M x N] = A[M x K] * Bt^T (+bias). Bt is [N][K] f16 (pre-transposed).
// ---------------------------------------------------------------------------
template <int K, int N, bool A_F32, bool OUT_F16>
__global__ __launch_bounds__(256, 2) void gemm_mfma(
    const void* __restrict__ A_, const _Float16* __restrict__ Bt,
    const float* __restrict__ bias, void* __restrict__ out)
{
  __shared__ _Float16 Blds[N * K];  // 64 KB

  const int tid = threadIdx.x;
  constexpr int CHUNKS = K / 8;
  constexpr int ITER = (N * K / 8) / 256;
#pragma unroll
  for (int i = 0; i < ITER; ++i) {
    int idx = tid + i * 256;
    int n = idx / CHUNKS;
    int c = idx % CHUNKS;
    int cs = c ^ (n & 7);
    *(uint4*)(Blds + (size_t)n * K + cs * 8) =
        *(const uint4*)(Bt + (size_t)n * K + c * 8);
  }
  __syncthreads();

  const int w = tid >> 6, l = tid & 63;
  const int lm = l & 15, lq = l >> 4;
  const size_t m0 = (size_t)blockIdx.x * 128;

  float4v acc[2][N / 16] = {};

#pragma unroll
  for (int kk = 0; kk < K / 32; ++kk) {
    const int kbase = kk * 32 + lq * 8;
    half8v af[2];
#pragma unroll
    for (int ms = 0; ms < 2; ++ms) {
      const size_t row = m0 + (size_t)(w * 2 + ms) * 16 + lm;
      if constexpr (A_F32) {
        const float* ap = (const float*)A_ + row * K + kbase;
        float4 x0 = *(const float4*)ap;
        float4 x1 = *(const float4*)(ap + 4);
        af[ms] = half8v{(_Float16)x0.x, (_Float16)x0.y, (_Float16)x0.z, (_Float16)x0.w,
                        (_Float16)x1.x, (_Float16)x1.y, (_Float16)x1.z, (_Float16)x1.w};
      } else {
        af[ms] = *(const half8v*)((const _Float16*)A_ + row * K + kbase);
      }
    }
    const int c = kk * 4 + lq;
#pragma unroll
    for (int nt = 0; nt < N / 16; ++nt) {
      const int n = nt * 16 + lm;
      half8v bf = *(const half8v*)(Blds + (size_t)n * K + (c ^ (lm & 7)) * 8);
      acc[0][nt] = __builtin_amdgcn_mfma_f32_16x16x32_f16(af[0], bf, acc[0][nt], 0, 0, 0);
      acc[1][nt] = __builtin_amdgcn_mfma_f32_16x16x32_f16(af[1], bf, acc[1][nt], 0, 0, 0);
    }
  }

#pragma unroll
  for (int ms = 0; ms < 2; ++ms) {
    const size_t rowbase = m0 + (size_t)(w * 2 + ms) * 16 + lq * 4;
#pragma unroll
    for (int nt = 0; nt < N / 16; ++nt) {
      const int col = nt * 16 + lm;
      const float bcol = bias[col];
#pragma unroll
      for (int rr = 0; rr < 4; ++rr) {
        const size_t row = rowbase + rr;
        float v = acc[ms][nt][rr] + bcol;
        if constexpr (OUT_F16) ((_Float16*)out)[row * N + col] = (_Float16)v;
        else                   ((float*)out)[row * N + col] = v;
      }
    }
  }
}

// ---------------------------------------------------------------------------
// Sequential scan. One WG (512 thr, 8 waves) per batch element.
//  r7's 2-batch experiment showed clean serialization -> the step is bound by
//  the PER-WAVE instruction stream (fdot2 ~4cy VOP3P) + shared LDS pipe, not
//  raw latency. Two changes vs the r5 structure:
//  1) ALL 8 waves do candidate work (32 cols each; lane computes 2 col
//     partials over its 64-k slice = 64 fdot2, reduce = 4 shfl_xor). The
//     z-burst (16 MFMA/wave) and global staging (u32/thread) also split
//     8-way. Per-wave VALU stream halves; burst MFMA overlaps candidate
//     fdot2 in-wave on separate pipes; no wave idles.
//  2) zhS re-laid as [8][4][72]: the old zhS[t][q*64] slice reads put all 4
//     quad addresses on banks 0-3 (128B = 32 banks apart) -> 4-way conflict
//     on the hottest reads every step since r2. Slice pitch 144B == 4 banks
//     -> quads hit disjoint bank quads.
//  Schedule/barriers: identical 5-per-group (B0..B3 + B4) verified schedule.
// ---------------------------------------------------------------------------
__global__ __launch_bounds__(512, 1) void scan_kernel(
    const u32* __restrict__ xz32, const u32* __restrict__ xh32,
    const float* __restrict__ Uz, const float* __restrict__ Uh,
    u32* __restrict__ hsOut)
{
  const int b   = blockIdx.x;
  const int tid = threadIdx.x;
  const int w   = tid >> 6;
  const int l   = tid & 63;
  const int lm  = l & 15;
  const int q   = l >> 4;

  __shared__ __align__(16) u16 histS[8][264];   // h_t ring
  __shared__ __align__(16) u16 zringS[8][264];  // z_t ring
  __shared__ __align__(16) u16 zhS[8][4][72];   // z*h ring, slice q bank-disjoint
  __shared__ __align__(16) u16 xhS[2][1024];    // xh staging, 4 rows x 256
  __shared__ __align__(16) u16 xzS[2][1024];    // xz staging, 4 rows x 256

  uint4 WH0[8], WH1[8];  // Uh cols w*32+lm / +16, k-slice q*64+i*8..
  uint4 WZ[16];          // Uz B-frags, cols w*32+nt*16+lm

  const size_t xb32 = (size_t)b * 4096 * 128;   // u32 units
  const size_t bt4  = (size_t)b * 4096;
  const int c   = w * 32 + (l & 31);  // owned candidate column
  const int csl = c >> 6;             // zh slice of owned col
  const int co  = c & 63;
  const int cw0 = w * 32 + lm;
  const int cw1 = cw0 + 16;
  const int srr = tid >> 7;           // staging row 0..3
  const int scc = tid & 127;          // staging u32 col

  // ---- weights (all waves load both candidate + burst weights) ----
#pragma unroll
  for (int i = 0; i < 8; ++i) {
    u32 qa[4], qb[4];
#pragma unroll
    for (int p2 = 0; p2 < 4; ++p2) {
      int k0 = q * 64 + i * 8 + 2 * p2;
      qa[p2] = pack2(Uh[(size_t)k0 * 256 + cw0], Uh[(size_t)(k0 + 1) * 256 + cw0]);
      qb[p2] = pack2(Uh[(size_t)k0 * 256 + cw1], Uh[(size_t)(k0 + 1) * 256 + cw1]);
    }
    WH0[i] = make_uint4(qa[0], qa[1], qa[2], qa[3]);
    WH1[i] = make_uint4(qb[0], qb[1], qb[2], qb[3]);
  }
#pragma unroll
  for (int kt = 0; kt < 8; ++kt)
#pragma unroll
    for (int nt = 0; nt < 2; ++nt) {
      u32 q2[4];
#pragma unroll
      for (int p2 = 0; p2 < 4; ++p2) {
        int k0 = kt * 32 + q * 8 + 2 * p2;
        int cn = w * 32 + nt * 16 + lm;
        q2[p2] = pack2(Uz[(size_t)k0 * 256 + cn], Uz[(size_t)(k0 + 1) * 256 + cn]);
      }
      WZ[kt * 2 + nt] = make_uint4(q2[0], q2[1], q2[2], q2[3]);
    }

  // zero h_{-4..-1} (slots 4..7) and zh slot 0
  for (int i = tid; i < 4 * 264; i += 512) (&histS[4][0])[i] = 0;
  for (int i = tid; i < 4 * 72; i += 512) (&zhS[0][0][0])[i] = 0;

  {
    // all threads: z_0..3 = sigmoid(xz rows 0..3); stage xh 0..3, xz 4..7
    u32 xzv = xz32[(bt4 + srr) * 128 + scc];
    half2v a0 = uph(xzv);
    *(u32*)&zringS[srr][scc * 2] = pack2(sigmoid_f((float)a0.x), sigmoid_f((float)a0.y));
    *(u32*)&xhS[0][srr * 256 + scc * 2] = xh32[xb32 + (size_t)srr * 128 + scc];
    *(u32*)&xzS[0][srr * 256 + scc * 2] = xz32[(bt4 + 4 + srr) * 128 + scc];
  }
  float h = 0.f;
  __syncthreads();

  for (int tb = 0; tb < 4096; tb += 4) {
    const int p = (tb >> 2) & 1;
    u32 xhv, xzv;                       // staged in regs u0 -> u2
#pragma unroll
    for (int u = 0; u < 4; ++u) {
      const int t = tb + u;

      // -------- global traffic, 8-way split (one u32 per thread) --------
      if (u == 0) {
        int rh = tb + 4 + srr; if (rh > 4095) rh = 4095;
        int rz = tb + 8 + srr; if (rz > 4095) rz = 4095;
        xhv = xh32[xb32 + (size_t)rh * 128 + scc];
        xzv = xz32[(bt4 + rz) * 128 + scc];
        if (tb > 0) {
          int ro = tb - 4 + srr;
          hsOut[xb32 + (size_t)ro * 128 + scc] = *(const u32*)&histS[ro & 7][scc * 2];
        }
      } else if (u == 2) {
        *(u32*)&xhS[p ^ 1][srr * 256 + scc * 2] = xhv;
        *(u32*)&xzS[p ^ 1][srr * 256 + scc * 2] = xzv;
      }

      // -------- z-burst (u==3): issue first, MFMA overlaps fdot2 --------
      float4v acc0 = {}, acc1 = {};
      if (u == 3) {
        const int srow = (tb + 7 + (l & 3)) & 7;   // m%4 row select
        const int koff = q * 8;
#pragma unroll
        for (int kt = 0; kt < 8; ++kt) {
          half8v a = __builtin_bit_cast(
              half8v, *(const uint4*)&histS[srow][kt * 32 + koff]);
          acc0 = __builtin_amdgcn_mfma_f32_16x16x32_f16(
              a, __builtin_bit_cast(half8v, WZ[kt * 2 + 0]), acc0, 0, 0, 0);
          acc1 = __builtin_amdgcn_mfma_f32_16x16x32_f16(
              a, __builtin_bit_cast(half8v, WZ[kt * 2 + 1]), acc1, 0, 0, 0);
        }
      }

      // -------- candidate gate: 2 partial cols, reduce, own 1 col --------
      float xh_t = h16tof(xhS[p][u * 256 + c]);
      float z_t  = h16tof(zringS[t & 7][c]);
      u16 zn = (u < 3) ? zringS[(t + 1) & 7][c] : (u16)0;
      const uint4* a4 = (const uint4*)&zhS[t & 7][q][0];
      float s0 = 0.f, s1 = 0.f;
#pragma unroll
      for (int i = 0; i < 8; ++i) {
        uint4 A = a4[i];
        uint4 w0 = WH0[i], w1 = WH1[i];
        s0 = fdot2(uph(A.x), uph(w0.x), s0);
        s0 = fdot2(uph(A.y), uph(w0.y), s0);
        s0 = fdot2(uph(A.z), uph(w0.z), s0);
        s0 = fdot2(uph(A.w), uph(w0.w), s0);
        s1 = fdot2(uph(A.x), uph(w1.x), s1);
        s1 = fdot2(uph(A.y), uph(w1.y), s1);
        s1 = fdot2(uph(A.z), uph(w1.z), s1);
        s1 = fdot2(uph(A.w), uph(w1.w), s1);
      }
      // reduce across the 4 quads (k-slices); both totals kept on all lanes
      s0 += __shfl_xor(s0, 32);
      s1 += __shfl_xor(s1, 32);
      s0 += __shfl_xor(s0, 16);
      s1 += __shfl_xor(s1, 16);
      float pre = (q & 1) ? s1 : s0;    // owned col: (l&31) = (q&1)*16 + lm
      float htl = tanh_f(pre + xh_t);
      h += z_t * (htl - h);
      histS[t & 7][c] = ftoh16(h);      // 2 lanes/col write same value

      if (u < 3) {
        zhS[(t + 1) & 7][csl][co] = ftoh16(h16tof(zn) * h);
        barrier_lgkm();                 // B_u
      } else {
        // burst epilogue: quad q handles time-row q (2 sigmoids/lane)
        float e0 = q == 0 ? acc0[0] : q == 1 ? acc0[1] : q == 2 ? acc0[2] : acc0[3];
        float e1 = q == 0 ? acc1[0] : q == 1 ? acc1[1] : q == 2 ? acc1[2] : acc1[3];
        int cn0 = w * 32 + lm, cn1 = cn0 + 16;
        float z0 = sigmoid_f(e0 + h16tof(xzS[p][q * 256 + cn0]));
        float z1 = sigmoid_f(e1 + h16tof(xzS[p][q * 256 + cn1]));
        zringS[(tb + 4 + q) & 7][cn0] = ftoh16(z0);
        zringS[(tb + 4 + q) & 7][cn1] = ftoh16(z1);
        barrier_lgkm();                 // B3 (publishes z_{tb+4})
        float znb = h16tof(zringS[(tb + 4) & 7][c]);
        zhS[(tb + 4) & 7][csl][co] = ftoh16(znb * h);
        barrier_lgkm();                 // B4 (publishes zh_{tb+4})
      }
    }
  }

  // tail: write back h rows 4092..4095 (all threads)
  {
    int ro = 4092 + srr;
    hsOut[xb32 + (size_t)ro * 128 + scc] = *(const u32*)&histS[ro & 7][scc * 2];
  }
}

// ---------------------------------------------------------------------------
extern "C" void kernel_launch(void* const* d_in, const int* in_sizes, int n_in,
                              void* d_out, int out_size, void* d_ws, size_t ws_size,
                              hipStream_t stream)
{
  (void)in_sizes; (void)n_in; (void)out_size; (void)ws_size;
  const float* x  = (const float*)d_in[0];
  const float* Wz = (const float*)d_in[1];
  const float* Uz = (const float*)d_in[2];
  const float* bz = (const float*)d_in[3];
  const float* Wh = (const float*)d_in[4];
  const float* Uh = (const float*)d_in[5];
  const float* bh = (const float*)d_in[6];
  const float* Wo = (const float*)d_in[7];
  const float* bo = (const float*)d_in[8];

  char* ws = (char*)d_ws;
  _Float16* Wzt  = (_Float16*)(ws);                                   // 64 KB
  _Float16* Wht  = (_Float16*)(ws + (64 << 10));                      // 64 KB
  _Float16* Wot  = (_Float16*)(ws + (128 << 10));                     // 64 KB
  _Float16* xz16 = (_Float16*)(ws + (256 << 10));                     // 64 MB
  _Float16* xh16 = (_Float16*)(ws + (256 << 10) + (size_t)64 * 1024 * 1024); // 64 MB

  _Float16* hs16 = (_Float16*)d_out;  // hs staged in d_out; head GEMM in-place

  prep_transpose<<<dim3(32, 3), 256, 0, stream>>>(Wz, Wh, Wo, Wzt, Wht, Wot);
  gemm_mfma<128, 256, true, true><<<1024, 256, 0, stream>>>(x, Wzt, bz, xz16);
  gemm_mfma<128, 256, true, true><<<1024, 256, 0, stream>>>(x, Wht, bh, xh16);
  scan_kernel<<<32, 512, 0, stream>>>((const u32*)xz16, (const u32*)xh16,
                                      Uz, Uh, (u32*)d_out);
  gemm_mfma<256, 128, false, false><<<1024, 256, 0, stream>>>(hs16, Wot, bo, d_out);
}